// Round 5
// baseline (186.144 us; speedup 1.0000x reference)
//
#include <hip/hip_runtime.h>
#include <stdint.h>

// Geometry from reference: B=16, E=1024, H=1024, H4=4096, K_total = E+H = 2048.
// Inputs are FLOAT32 and output is FLOAT32 (reference dtypes; verified by the
// round-4 failure signature: bf16 u16-pair writes reinterpreted as f32 put
// c_new-magnitude values (~3) into output 0).
#define H4_ 4096
#define B_  16

// ---- K1: ifgo partials. part[s][b][j] f32. grid = 128*split blocks x 256 thr.
// Block (ct, s): 32 consecutive cols j0 = ct*32 (one 128B line), K-chunks
// [s*chunks, (s+1)*chunks), chunk = 256 K-rows (chunks 0..3 = Wi/x, 4..7 = Wh/h).
__global__ __launch_bounds__(256) void k1_gemm(
    const float* __restrict__ x, const float* __restrict__ h,
    const float* __restrict__ Wi, const float* __restrict__ Wh,
    float* __restrict__ part, int chunks)
{
    __shared__ float a_lds[256][16];      // 16 KB: A chunk, [k_local][batch]
    __shared__ float red[8][16][32];      // 16 KB: [k-stripe][b][c]

    const int ct = blockIdx.x & 127;
    const int s  = blockIdx.x >> 7;
    const int j0 = ct * 32;
    const int t  = threadIdx.x;
    const int c8 = t & 7;                 // col quad index (8 x 4 cols = 32)
    const int bq = (t >> 3) & 3;          // batch quad
    const int ks = t >> 5;                // k-stripe 0..7 (32 rows each)

    float acc[4][4];
    #pragma unroll
    for (int r = 0; r < 4; r++)
        #pragma unroll
        for (int c = 0; c < 4; c++) acc[r][c] = 0.f;

    const int m_beg = s * chunks, m_end = m_beg + chunks;
    for (int m = m_beg; m < m_end; ++m) {
        const float* A  = (m < 4) ? x : h;   // [16][1024] f32
        const float* W  = (m < 4) ? Wi : Wh; // [1024][4096] f32
        const int    e0 = (m & 3) * 256;

        // stage A chunk -> LDS: a_lds[kl][b] = A[b][e0+kl]
        {
            const int b = t & 15, kc = t >> 4;        // 16 k's per thread
            const float* src = A + b * 1024 + e0 + kc * 16;  // 64B aligned
            float4 v0 = *(const float4*)(src);
            float4 v1 = *(const float4*)(src + 4);
            float4 v2 = *(const float4*)(src + 8);
            float4 v3 = *(const float4*)(src + 12);
            const float vv[16] = { v0.x, v0.y, v0.z, v0.w, v1.x, v1.y, v1.z, v1.w,
                                   v2.x, v2.y, v2.z, v2.w, v3.x, v3.y, v3.z, v3.w };
            #pragma unroll
            for (int j = 0; j < 16; j++) a_lds[kc * 16 + j][b] = vv[j];
        }
        __syncthreads();

        const float* wp = W + (size_t)e0 * H4_ + j0 + c8 * 4;
        #pragma unroll 8
        for (int i = 0; i < 32; i++) {
            const int kl = ks * 32 + i;               // row e0+kl <= 1023
            float4 w = *(const float4*)(wp + (size_t)kl * H4_);  // 4 cols, 16B
            float4 a = *(const float4*)&a_lds[kl][bq * 4];       // 4 batches
            acc[0][0] += a.x * w.x; acc[0][1] += a.x * w.y; acc[0][2] += a.x * w.z; acc[0][3] += a.x * w.w;
            acc[1][0] += a.y * w.x; acc[1][1] += a.y * w.y; acc[1][2] += a.y * w.z; acc[1][3] += a.y * w.w;
            acc[2][0] += a.z * w.x; acc[2][1] += a.z * w.y; acc[2][2] += a.z * w.z; acc[2][3] += a.z * w.w;
            acc[3][0] += a.w * w.x; acc[3][1] += a.w * w.y; acc[3][2] += a.w * w.z; acc[3][3] += a.w * w.w;
        }
        __syncthreads();                  // before next chunk overwrites a_lds
    }

    // cross-stripe reduction (8 ks)
    #pragma unroll
    for (int r = 0; r < 4; r++)
        *(float4*)&red[ks][bq * 4 + r][c8 * 4] =
            make_float4(acc[r][0], acc[r][1], acc[r][2], acc[r][3]);
    __syncthreads();
    {
        const int b = t >> 4, c = t & 15;   // each thread: cols c and c+16
        float s0 = 0.f, s1 = 0.f;
        #pragma unroll
        for (int kk = 0; kk < 8; kk++) {
            s0 += red[kk][b][c];
            s1 += red[kk][b][c + 16];
        }
        float* dst = part + ((size_t)s * B_ + b) * H4_ + j0;
        dst[c]      = s0;
        dst[c + 16] = s1;
    }
}

// ---- K2: sum split partials + biases, activations. out = [h_new | c_new] f32
__global__ __launch_bounds__(256) void k2_act(
    const float* __restrict__ part, const float* __restrict__ c,
    const float* __restrict__ Wi_b, const float* __restrict__ Wh_b,
    float* __restrict__ out, int split)
{
    const int tg = blockIdx.x * 256 + threadIdx.x;   // 0..16383
    const int b  = tg >> 10;
    const int j  = tg & 1023;

    float g4[4];
    #pragma unroll
    for (int g = 0; g < 4; g++) {
        const int col = g * 1024 + j;
        float acc = Wi_b[col] + Wh_b[col];
        for (int ss = 0; ss < split; ss++)
            acc += part[((size_t)ss * B_ + b) * H4_ + col];
        g4[g] = acc;
    }
    const float ig = 1.f / (1.f + __expf(-g4[0]));
    const float fg = 1.f / (1.f + __expf(-g4[1]));
    const float gg = tanhf(g4[2]);
    const float og = 1.f / (1.f + __expf(-g4[3]));
    const float cv = c[tg];
    const float cn = fg * cv + ig * gg;
    const float hn = og * tanhf(cn);
    out[tg]         = hn;
    out[16384 + tg] = cn;
}

// ---- Fallback: fully fused, zero workspace. grid = 64 blocks x 256 thr.
__global__ __launch_bounds__(256) void k_fused(
    const float* __restrict__ x, const float* __restrict__ h,
    const float* __restrict__ cin,
    const float* __restrict__ Wi, const float* __restrict__ Wh,
    const float* __restrict__ Wi_b, const float* __restrict__ Wh_b,
    float* __restrict__ out)
{
    __shared__ float a_lds[256][16];
    __shared__ float red[16][16][16];
    __shared__ float gate_s[4][16][16];

    const int j0 = blockIdx.x * 16;       // 16 h-columns
    const int t  = threadIdx.x;
    const int ks = t >> 4;                // 16 stripes of 16 rows
    const int bq = (t >> 2) & 3;
    const int c4 = t & 3;

    float acc[4][4][4];                   // [gate][batch][col]
    #pragma unroll
    for (int g = 0; g < 4; g++)
        #pragma unroll
        for (int r = 0; r < 4; r++)
            #pragma unroll
            for (int c = 0; c < 4; c++) acc[g][r][c] = 0.f;

    for (int m = 0; m < 8; ++m) {
        const float* A  = (m < 4) ? x : h;
        const float* W  = (m < 4) ? Wi : Wh;
        const int    e0 = (m & 3) * 256;
        {
            const int b = t & 15, kc = t >> 4;
            const float* src = A + b * 1024 + e0 + kc * 16;
            float4 v0 = *(const float4*)(src);
            float4 v1 = *(const float4*)(src + 4);
            float4 v2 = *(const float4*)(src + 8);
            float4 v3 = *(const float4*)(src + 12);
            const float vv[16] = { v0.x, v0.y, v0.z, v0.w, v1.x, v1.y, v1.z, v1.w,
                                   v2.x, v2.y, v2.z, v2.w, v3.x, v3.y, v3.z, v3.w };
            #pragma unroll
            for (int jj = 0; jj < 16; jj++) a_lds[kc * 16 + jj][b] = vv[jj];
        }
        __syncthreads();
        #pragma unroll 4
        for (int i = 0; i < 16; i++) {
            const int kl = ks * 16 + i;
            float4 a = *(const float4*)&a_lds[kl][bq * 4];
            const float av[4] = { a.x, a.y, a.z, a.w };
            #pragma unroll
            for (int g = 0; g < 4; g++) {
                float4 w = *(const float4*)(W + (size_t)(e0 + kl) * H4_ + g * 1024 + j0 + c4 * 4);
                #pragma unroll
                for (int r = 0; r < 4; r++) {
                    acc[g][r][0] += av[r] * w.x; acc[g][r][1] += av[r] * w.y;
                    acc[g][r][2] += av[r] * w.z; acc[g][r][3] += av[r] * w.w;
                }
            }
        }
        __syncthreads();
    }

    #pragma unroll
    for (int g = 0; g < 4; g++) {
        #pragma unroll
        for (int r = 0; r < 4; r++)
            *(float4*)&red[ks][bq * 4 + r][c4 * 4] =
                make_float4(acc[g][r][0], acc[g][r][1], acc[g][r][2], acc[g][r][3]);
        __syncthreads();
        {
            const int b = t >> 4, c = t & 15;
            float sum = 0.f;
            #pragma unroll
            for (int kk = 0; kk < 16; kk++) sum += red[kk][b][c];
            gate_s[g][b][c] = sum;
        }
        __syncthreads();
    }

    {
        const int b = t >> 4, jj = t & 15;
        const int j = j0 + jj;
        const float s0 = gate_s[0][b][jj] + Wi_b[j]        + Wh_b[j];
        const float s1 = gate_s[1][b][jj] + Wi_b[1024 + j] + Wh_b[1024 + j];
        const float s2 = gate_s[2][b][jj] + Wi_b[2048 + j] + Wh_b[2048 + j];
        const float s3 = gate_s[3][b][jj] + Wi_b[3072 + j] + Wh_b[3072 + j];
        const float ig = 1.f / (1.f + __expf(-s0));
        const float fg = 1.f / (1.f + __expf(-s1));
        const float gg = tanhf(s2);
        const float og = 1.f / (1.f + __expf(-s3));
        const float cv = cin[b * 1024 + j];
        const float cn = fg * cv + ig * gg;
        const float hn = og * tanhf(cn);
        out[b * 1024 + j]         = hn;
        out[16384 + b * 1024 + j] = cn;
    }
}

extern "C" void kernel_launch(void* const* d_in, const int* in_sizes, int n_in,
                              void* d_out, int out_size, void* d_ws, size_t ws_size,
                              hipStream_t stream) {
    (void)in_sizes; (void)n_in; (void)out_size;
    const float* x    = (const float*)d_in[0];
    const float* h    = (const float*)d_in[1];
    const float* c    = (const float*)d_in[2];
    // d_in[3] = context (dead: multiplied by 0 in reference)
    const float* Wi   = (const float*)d_in[4];
    const float* Wi_b = (const float*)d_in[5];
    const float* Wh   = (const float*)d_in[6];
    const float* Wh_b = (const float*)d_in[7];
    // d_in[8..11] = AZ_* (dead)

    float* part = (float*)d_ws;
    float* out  = (float*)d_out;

    const size_t need1 = (size_t)B_ * H4_ * sizeof(float);  // 256 KB per split
    int split = 0;
    if      (ws_size >= 4 * need1) split = 4;
    else if (ws_size >= 2 * need1) split = 2;
    else if (ws_size >= 1 * need1) split = 1;

    if (split > 0) {
        k1_gemm<<<128 * split, 256, 0, stream>>>(x, h, Wi, Wh, part, 8 / split);
        k2_act<<<64, 256, 0, stream>>>(part, c, Wi_b, Wh_b, out, split);
    } else {
        k_fused<<<64, 256, 0, stream>>>(x, h, c, Wi, Wh, Wi_b, Wh_b, out);
    }
}